// Round 1
// baseline (172.378 us; speedup 1.0000x reference)
//
#include <hip/hip_runtime.h>
#include <math.h>

typedef float f4 __attribute__((ext_vector_type(4)));

#define TOKENS 16384
#define DIM 4096
#define NE 64
#define KTOP 8
#define BM 64
#define BK 64
#define NT 256
#define NBLK (TOKENS / BM) /* 256 */

// K1: gate GEMM + softmax + top-8. One block = 64 tokens x all 64 experts.
// LDS XOR swizzle at float4 granularity: element [kk][m] lives at
//   kk*64 + (((m>>2) ^ (kk>>2)) & 15)*4 + (m&3)
// -> transposed staging writes are 2-way-max bank conflicts (free, m136),
//    and compute reads are 16B-aligned ds_read_b128.
__global__ __launch_bounds__(NT) void gate_topk_kernel(
    const float* __restrict__ x, const float* __restrict__ W,
    const float* __restrict__ bias, float* __restrict__ idx_out,
    float* __restrict__ val_out, float* __restrict__ blocksums)
{
    __shared__ float As[BK * BM];
    __shared__ float Bs[BK * NE];
    __shared__ float Ls[BM][NE + 1];   // stride 65: row scans are 2-way max

    const int tid = threadIdx.x;
    // staging mapping
    const int kq = tid & 15;   // float4 index along K
    const int mg = tid >> 4;   // base row (0..15), rows mg+16s
    // compute mapping (16x16 thread grid, 4x4 register tile)
    const int tx = tid & 15;
    const int ty = tid >> 4;
    const int tm = ty << 2;
    const int tn = tx << 2;
    const int row0 = blockIdx.x * BM;

    float bj[4];
#pragma unroll
    for (int j = 0; j < 4; ++j) bj[j] = bias[tn + j];

    const float* xa0 = x + (size_t)(row0 + mg) * DIM + (kq << 2);
    const float* wb0 = W + (size_t)mg * DIM + (kq << 2);

    float acc[4][4] = {};
    f4 fa[4], fb[4];
#pragma unroll
    for (int s = 0; s < 4; ++s) {
        fa[s] = *(const f4*)(xa0 + (size_t)(16 * s) * DIM);
        fb[s] = *(const f4*)(wb0 + (size_t)(16 * s) * DIM);
    }

    for (int kt = 0; kt < DIM / BK; ++kt) {
        __syncthreads();   // previous tile's reads done
#pragma unroll
        for (int s = 0; s < 4; ++s) {
            const int m = mg + (s << 4);
            const int c4 = ((m >> 2) ^ kq) & 15;
            const int base = (kq << 2) * BM + (c4 << 2) + (m & 3);
#pragma unroll
            for (int j = 0; j < 4; ++j) {
                As[base + (j << 6)] = fa[s][j];
                Bs[base + (j << 6)] = fb[s][j];
            }
        }
        __syncthreads();
        if (kt + 1 < DIM / BK) {   // prefetch next tile into regs (hides HBM under FMAs)
            const int ko = (kt + 1) * BK;
#pragma unroll
            for (int s = 0; s < 4; ++s) {
                fa[s] = *(const f4*)(xa0 + (size_t)(16 * s) * DIM + ko);
                fb[s] = *(const f4*)(wb0 + (size_t)(16 * s) * DIM + ko);
            }
        }
        // two-level accumulation: fresh accumulator per K-tile, fold at end
        // (cuts serial-sum rounding ~5x; top-k idx output is tie-sensitive)
        float acct[4][4] = {};
#pragma unroll
        for (int kk = 0; kk < BK; ++kk) {
            const int kq2 = kk >> 2;
            const f4 a4 = *(const f4*)&As[kk * BM + (((ty ^ kq2) & 15) << 2)];
            const f4 b4 = *(const f4*)&Bs[kk * NE + (((tx ^ kq2) & 15) << 2)];
#pragma unroll
            for (int i = 0; i < 4; ++i)
#pragma unroll
                for (int j = 0; j < 4; ++j)
                    acct[i][j] = fmaf(a4[i], b4[j], acct[i][j]);
        }
#pragma unroll
        for (int i = 0; i < 4; ++i)
#pragma unroll
            for (int j = 0; j < 4; ++j)
                acc[i][j] += acct[i][j];
    }

    // ---- epilogue: logits -> LDS, per-token softmax + top-8 ----
#pragma unroll
    for (int i = 0; i < 4; ++i)
#pragma unroll
        for (int j = 0; j < 4; ++j)
            Ls[tm + i][tn + j] = acc[i][j] + bj[j];
    __syncthreads();

    float lsum = 0.0f;
    if (tid < BM) {   // wave 0: one lane per token
        const int m = tid;
        const int token = row0 + m;
        float mx = -INFINITY;
        for (int e = 0; e < NE; ++e) mx = fmaxf(mx, Ls[m][e]);
        float sum = 0.0f;
        for (int e = 0; e < NE; ++e) {
            float p = expf(Ls[m][e] - mx);
            Ls[m][e] = p;
            sum += p;
        }
#pragma unroll
        for (int j = 0; j < KTOP; ++j) {
            float best = -1.0f; int be = 0;
            for (int e = 0; e < NE; ++e) {          // strict > : lowest index on tie,
                float v = Ls[m][e];                 // descending order = lax.top_k
                if (v > best) { best = v; be = e; }
            }
            Ls[m][be] = -1.0f;
            const float val = best / sum;           // softmax value (same op order as ref)
            idx_out[token * KTOP + j] = (float)be;  // d_out read back as flat f32
            val_out[token * KTOP + j] = val;        // raw; normalized by K2
            lsum += val;
        }
    }
    if (tid < 64) {   // wave-0 shuffle reduce (deterministic, no atomics)
#pragma unroll
        for (int off = 32; off > 0; off >>= 1)
            lsum += __shfl_down(lsum, off, 64);
        if (tid == 0) blocksums[blockIdx.x] = lsum;
    }
}

// K2: global normalization weights = vals / sum(all vals).
// Every thread computes the same serial sum of 256 partials (uniform ->
// scalarized, deterministic), then divides in place.
__global__ __launch_bounds__(256) void scale_kernel(
    const float* __restrict__ blocksums, float* __restrict__ vals)
{
    float total = 0.0f;
    for (int i = 0; i < NBLK; ++i) total += blocksums[i];
    const int i = blockIdx.x * blockDim.x + threadIdx.x;
    vals[i] = vals[i] / total;
}

extern "C" void kernel_launch(void* const* d_in, const int* in_sizes, int n_in,
                              void* d_out, int out_size, void* d_ws, size_t ws_size,
                              hipStream_t stream)
{
    const float* x = (const float*)d_in[0];
    const float* W = (const float*)d_in[1];
    const float* b = (const float*)d_in[2];
    float* idx_out = (float*)d_out;
    float* val_out = idx_out + (size_t)TOKENS * KTOP;
    float* blocksums = (float*)d_ws;

    gate_topk_kernel<<<NBLK, NT, 0, stream>>>(x, W, b, idx_out, val_out, blocksums);
    scale_kernel<<<(TOKENS * KTOP) / 256, 256, 0, stream>>>(blocksums, val_out);
}